// Round 11
// baseline (220.431 us; speedup 1.0000x reference)
//
#include <hip/hip_runtime.h>
#include <hip/hip_bf16.h>

#define NROWS 4096
#define NLAB  2048
#define NPAIR 2048
#define PADW  2052                  // P2 row stride in floats (pad 4)
#define SIDX(p) ((p) + ((p) >> 5))  // s2 swizzle: +1 float per 32 -> 2-way max

typedef __attribute__((ext_vector_type(8))) short short8;
typedef __attribute__((ext_vector_type(4))) float f32x4;

__device__ __forceinline__ unsigned short f2bf(float x) {
  unsigned int u = __float_as_uint(x);
  unsigned int r = u + 0x7fffu + ((u >> 16) & 1u);   // RNE, no NaN in data
  return (unsigned short)(r >> 16);
}

// ---- prep (1024 blocks x 256): per wave = one original row: rank by counting
//      sort, write bf16 feature row + norm at SORTED slot; pair metadata ----
__global__ __launch_bounds__(256) void prep_kernel(const float* __restrict__ labels,
                                                   const float* __restrict__ z1,
                                                   const float* __restrict__ z2,
                                                   unsigned short* __restrict__ Fb,
                                                   float* __restrict__ rs,
                                                   float* __restrict__ ssorted2,
                                                   int* __restrict__ pl2v) {
  __shared__ float L[NLAB];
  const int tid = threadIdx.x;
  const int lane = tid & 63, wid = tid >> 6;
  for (int t = tid; t < NLAB; t += 256) L[t] = labels[t];
  __syncthreads();
  const int i = blockIdx.x * 4 + wid;               // original row in [0,4096)
  const float a = L[i & (NLAB - 1)];
  int combo = 0;                                     // cnt | cntLE<<13
  #pragma unroll 4
  for (int jj = 0; jj < NLAB / 64; ++jj) {
    const int j = jj * 64 + lane;
    const float l = L[j];
    if (l < a) combo += 2 + (2 << 13);
    else if (l == a) combo += ((j < i) + (j + NLAB < i)) + (2 << 13);
  }
  #pragma unroll
  for (int off = 32; off > 0; off >>= 1) combo += __shfl_down(combo, off, 64);
  combo = __shfl(combo, 0, 64);                      // broadcast rank to wave
  const int cnt = combo & 8191, cle = combo >> 13;
  const float* src = (i < NLAB) ? (z1 + (size_t)i * 256)
                                : (z2 + (size_t)(i - NLAB) * 256);
  float4 v = ((const float4*)src)[lane];
  ushort4 o;
  o.x = f2bf(v.x); o.y = f2bf(v.y); o.z = f2bf(v.z); o.w = f2bf(v.w);
  ((ushort4*)Fb)[(size_t)cnt * 64 + lane] = o;
  float ss = v.x * v.x + v.y * v.y + v.z * v.z + v.w * v.w;
  #pragma unroll
  for (int off = 32; off > 0; off >>= 1) ss += __shfl_down(ss, off, 64);
  if (lane == 0) {
    rs[cnt] = ss;
    if (!(cnt & 1)) {                                // even rank: pair representative
      ssorted2[cnt >> 1] = a;
      pl2v[cnt >> 1] = (cle >> 1) - 1;               // last pair p with s2[p] <= a
    }
  }
}

// ---- fused: block = 16 sorted rows. Phase 1: stream all 4096 cols via MFMA
//      (A = stream cols, B = block rows; lane owns 4 consecutive cols of its
//      row = 2 in-lane col-pairs -> single ds_write_b64, no scatter/atomic).
//      Phase 2: per-row prefix scan (16 chunks! R10 bugfix) + per-lane
//      64-consecutive-pair lazy-pointer queries. G never materialized. ----
__global__ __launch_bounds__(512, 1) void fused_kernel(const unsigned short* __restrict__ Fb,
                                                       const float* __restrict__ rs,
                                                       const float* __restrict__ ssorted2,
                                                       const int* __restrict__ pl2v,
                                                       float2* __restrict__ part) {
  __shared__ float s2s[NPAIR + NPAIR / 32];          // swizzled pair labels (8448 B)
  __shared__ float P2[16 * PADW];                    // per-row pair sums -> prefix (128 KB)
  __shared__ float lab16[16];
  __shared__ int   pl16[16];
  __shared__ float losr[8][16];                      // per-wave per-row losum partials
  __shared__ float Ptot16[16];
  __shared__ float ld16[16];
  const int tid = threadIdx.x;
  const int lane = tid & 63, w = tid >> 6;
  const int r16 = lane & 15, kg = lane >> 4;
  const int rowbase = blockIdx.x * 16;
  // phase 0: stage s2 (swizzled; scalar stores since SIDX breaks alignment), metadata
  {
    const float4 v = ((const float4*)ssorted2)[tid];
    const int p = tid * 4;                           // p..p+3 within one 32-run
    s2s[SIDX(p)] = v.x; s2s[SIDX(p) + 1] = v.y;
    s2s[SIDX(p) + 2] = v.z; s2s[SIDX(p) + 3] = v.w;
    if (tid < 16) {
      lab16[tid] = ssorted2[(rowbase + tid) >> 1];
      pl16[tid]  = pl2v[(rowbase + tid) >> 1];
    }
  }
  // phase 1: own row R = rowbase + r16; preload B-frags (row R, all K)
  const int R = rowbase + r16;
  const float ra = rs[R];
  short8 bfr[8];
  {
    const unsigned short* pb = Fb + (size_t)R * 256 + kg * 8;
    #pragma unroll
    for (int ks = 0; ks < 8; ++ks) bfr[ks] = *(const short8*)(pb + ks * 32);
  }
  float losum = 0.f;
  #pragma unroll 1
  for (int it = 0; it < 32; ++it) {
    const int tb = (w + it * 8) * 16;                // 16-col tile base
    const unsigned short* pa = Fb + (size_t)(tb + r16) * 256 + kg * 8;
    f32x4 acc = {0.f, 0.f, 0.f, 0.f};
    #pragma unroll
    for (int ks = 0; ks < 8; ++ks)
      acc = __builtin_amdgcn_mfma_f32_16x16x32_bf16(*(const short8*)(pa + ks * 32),
                                                    bfr[ks], acc, 0, 0, 0);
    // C: row (A-dim) = stream col = kg*4+rr, col (B-dim) = r16  [m89/R7-verified]
    const float4 rc = *(const float4*)(rs + tb + kg * 4);
    const float rcv[4] = {rc.x, rc.y, rc.z, rc.w};
    float wv[4];
    #pragma unroll
    for (int rr = 0; rr < 4; ++rr) {
      const int c = tb + kg * 4 + rr;
      const float sq = fmaxf(ra + rcv[rr] - 2.f * acc[rr], 0.f);
      float lo = -0.5f * __builtin_amdgcn_sqrtf(sq); // -dist / T(=2)
      const bool self = (c == R);
      lo = self ? 0.f : lo;
      losum += lo;
      wv[rr] = self ? 0.f : __expf(lo);
    }
    const int cp0 = (tb >> 1) + kg * 2;              // 2 in-lane col-pairs
    *(float2*)&P2[r16 * PADW + cp0] = make_float2(wv[0] + wv[1], wv[2] + wv[3]);
  }
  // losum: combine kg-groups (lanes r16, r16+16, +32, +48)
  losum += __shfl_down(losum, 32, 64);
  losum += __shfl_down(losum, 16, 64);
  if (lane < 16) losr[w][lane] = losum;
  __syncthreads();                                   // P2 fully written; s2s visible
  // phase 2a: per-row inclusive prefix over ALL 2048 pair sums (16 chunks of 128).
  // wave w -> rows 2w (lanes 0-31) and 2w+1 (lanes 32-63)
  const int half = lane >> 5, lh = lane & 31;
  const int r2 = 2 * w + half;
  float* __restrict__ Prow = &P2[r2 * PADW];
  float carry = 0.f;
  #pragma unroll
  for (int c = 0; c < 16; ++c) {                     // R10 FIX: 16 chunks (was 8)
    const int cp = c * 128 + lh * 4;
    const float4 v = *(const float4*)&Prow[cp];
    const float t0 = v.x, t1 = t0 + v.y, t2 = t1 + v.z, t3 = t2 + v.w;
    float x = t3;
    #pragma unroll
    for (int off = 1; off < 32; off <<= 1) {
      const float y = __shfl_up(x, off, 32);
      if (lh >= off) x += y;
    }
    const float base = carry + x - t3;
    *(float4*)&Prow[cp] = make_float4(base + t0, base + t1, base + t2, base + t3);
    carry += __shfl(x, 31, 32);
  }
  const float Ptot = carry;
  if (lh == 0) Ptot16[r2] = Ptot;
  // phase 2b: 64 consecutive pairs per lane; lazy monotone opposite pointers
  const float a2 = lab16[r2];
  const int pL2 = pl16[r2];
  const int p0 = lh * 64;
  int rR = -1, qL = -1; bool qInit = false;
  float logden = 0.f, prod = 1.f; int pm = 0;
  #pragma unroll 1
  for (int s = 0; s < 64; ++s) {
    const int p = p0 + s;
    const float sv = s2s[SIDX(p)];
    float W;                                         // weight of NON-qualifiers
    if (p <= pL2) {
      const float v = a2 - sv;                       // non-increasing in p
      if (rR < 0) { int lo = pL2 + 1, hi = NPAIR;
        while (lo < hi) { int m = (lo + hi) >> 1;
          if (s2s[SIDX(m)] - a2 >= v) hi = m; else lo = m + 1; } rR = lo; }
      else { while (rR > pL2 + 1 && s2s[SIDX(rR - 1)] - a2 >= v) --rR; }
      W = Prow[rR - 1] - Prow[p];
    } else {
      const float v = sv - a2;                       // non-decreasing in p
      if (!qInit) { int lo = 0, hi = pL2 + 1;
        while (lo < hi) { int m = (lo + hi) >> 1;
          if (a2 - s2s[SIDX(m)] >= v) lo = m + 1; else hi = m; } qL = lo - 1; qInit = true; }
      else { while (qL >= 0 && a2 - s2s[SIDX(qL)] < v) --qL; }
      W = Prow[p - 1] - (qL >= 0 ? Prow[qL] : 0.f);
    }
    prod *= (Ptot - W);                              // den = weight with v_j >= v
    if (++pm == 4) { logden += __logf(prod); prod = 1.f; pm = 0; }
  }
  #pragma unroll
  for (int off = 16; off > 0; off >>= 1) logden += __shfl_down(logden, off, 32);
  if (lh == 0) ld16[r2] = logden;
  __syncthreads();
  if (tid < 16) {
    float L = 0.f;
    #pragma unroll
    for (int ww = 0; ww < 8; ++ww) L += losr[ww][tid];
    part[rowbase + tid] = make_float2(L, 2.f * ld16[tid] - __logf(Ptot16[tid]));
  }
}

__global__ __launch_bounds__(512) void final_kernel(const float2* __restrict__ part,
                                                    float* __restrict__ out) {
  const int tid = threadIdx.x;
  double L = 0.0, D = 0.0;
  for (int t = tid; t < NROWS; t += 512) {
    float2 p = part[t];
    L += (double)p.x; D += (double)p.y;
  }
  const int lane = tid & 63, wid = tid >> 6;
  #pragma unroll
  for (int off = 32; off > 0; off >>= 1) {
    L += __shfl_down(L, off, 64);
    D += __shfl_down(D, off, 64);
  }
  __shared__ double sL[8], sD[8];
  if (lane == 0) { sL[wid] = L; sD[wid] = D; }
  __syncthreads();
  if (tid == 0) {
    double Ls = 0.0, Ds = 0.0;
    #pragma unroll
    for (int w = 0; w < 8; ++w) { Ls += sL[w]; Ds += sD[w]; }
    out[0] = (float)((Ds - Ls) / 16773120.0);       // (sum log den - sum lo)/(n(n-1))
  }
}

extern "C" void kernel_launch(void* const* d_in, const int* in_sizes, int n_in,
                              void* d_out, int out_size, void* d_ws, size_t ws_size,
                              hipStream_t stream) {
  (void)in_sizes; (void)n_in; (void)out_size; (void)ws_size;
  const float* z1     = (const float*)d_in[0];
  const float* z2     = (const float*)d_in[1];
  const float* labels = (const float*)d_in[2];
  float* out = (float*)d_out;

  char* ws = (char*)d_ws;
  float2* part           = (float2*)ws;                       // 32 KB
  float*  ssorted2       = (float*)(ws + 32768);              // 8 KB
  float*  rs             = (float*)(ws + 40960);              // 16 KB (sorted norms)
  int*    pl2v           = (int*)(ws + 57344);                // 8 KB
  unsigned short* Fb     = (unsigned short*)(ws + 131072);    // 2 MB bf16 sorted feats

  prep_kernel<<<1024, 256, 0, stream>>>(labels, z1, z2, Fb, rs, ssorted2, pl2v);
  fused_kernel<<<256, 512, 0, stream>>>(Fb, rs, ssorted2, pl2v, part);
  final_kernel<<<1, 512, 0, stream>>>(part, out);
}